// Round 12
// baseline (152.432 us; speedup 1.0000x reference)
//
#include <hip/hip_runtime.h>
#include <math.h>

// Problem constants
#define DD 256
#define TT 4096
#define NBATCH 8
#define BTOK 32768            // NBATCH*TT tokens
#define EPSF 1e-7f

typedef __attribute__((ext_vector_type(4))) float f32x4;
typedef __attribute__((ext_vector_type(8))) short bf16x8;

// ---------------- fast-math helpers (native v_exp/v_sin/v_cos/v_log/v_rcp) ----------------
__device__ __forceinline__ float softplusf(float x) {
  float e = __expf(-fabsf(x));
  return fmaxf(x, 0.f) + __logf(1.f + e);
}
__device__ __forceinline__ float bf2f(unsigned short u) {
  union { unsigned int i; float f; } v; v.i = ((unsigned int)u) << 16; return v.f;
}
__device__ __forceinline__ unsigned short f2bf(float f) {  // RTNE
  union { float f; unsigned int i; } v; v.f = f;
  unsigned int x = v.i;
  unsigned int lsb = (x >> 16) & 1u;
  x += 0x7fffu + lsb;
  return (unsigned short)(x >> 16);
}
// decay = exp(are + i*aim); forcing = (decay-1)/(exp_arg + eps*sign(re+eps))
__device__ __forceinline__ void decay_forcing(float are, float aim,
    float& dre, float& dim, float& fre, float& fim) {
  float e = __expf(are);
  float s = __sinf(aim), c = __cosf(aim);
  dre = e * c; dim = e * s;
  float sg = (are + EPSF >= 0.f) ? 1.f : -1.f;
  float denr = are + EPSF * sg;
  float deni = aim;
  float inv = __builtin_amdgcn_rcpf(denr * denr + deni * deni);
  float nr = dre - 1.f, ni = dim;
  fre = (nr * denr + ni * deni) * inv;
  fim = (ni * denr - nr * deni) * inv;
}
// async 16B global->LDS (linear dest: wave-uniform base + lane*16)
__device__ __forceinline__ void gl_lds16(const void* g, void* l) {
  __builtin_amdgcn_global_load_lds(
      (const __attribute__((address_space(1))) unsigned int*)g,
      (__attribute__((address_space(3))) unsigned int*)l, 16, 0, 0);
}

// ---------------- prep (fused): xcvt (8192 blocks) | wpack1 (512) | wpack3 (768) ----------------
__global__ __launch_bounds__(256) void prep(
    const float* __restrict__ x, unsigned short* __restrict__ Xb,
    const float* __restrict__ Win, unsigned short* __restrict__ Wp1,
    const float* __restrict__ Wout, const float* __restrict__ Wgate,
    unsigned short* __restrict__ Wp3)
{
  const int bid = blockIdx.x;
  if (bid < 8192) {
    size_t i = ((size_t)bid * 256 + threadIdx.x) * 4;
    float4 v = *reinterpret_cast<const float4*>(&x[i]);
    ushort4 u;
    u.x = f2bf(v.x); u.y = f2bf(v.y); u.z = f2bf(v.z); u.w = f2bf(v.w);
    *reinterpret_cast<ushort4*>(&Xb[i]) = u;
  } else if (bid < 8704) {
    const int p = bid - 8192;          // 0..511
    const int k = threadIdx.x;         // 0..255
    const int g = p >> 5, r = p & 31;
    const int src = (r < 16) ? (g * 16 + r) : (256 + g * 16 + (r - 16));
    Wp1[(size_t)p * 256 + k] = f2bf(Win[(size_t)src * 512 + k]);
  } else {
    const int p = bid - 8704;          // 0..767
    const float* src = (p < 512) ? (Wout + (size_t)p * 512)
                                 : (Wgate + (size_t)(p - 512) * 512);
    Wp3[(size_t)p * 512 + threadIdx.x] = f2bf(src[threadIdx.x]);
    Wp3[(size_t)p * 512 + threadIdx.x + 256] = f2bf(src[threadIdx.x + 256]);
  }
}

// ---------------- K1: MFMA GEMM (M=32768, K=256, N=512 packed) + forcing epilogue ----------------
// Epilogue writes X_scan packed (re|im bf16 in one uint) -> Xri [BTOK][256].
__global__ __launch_bounds__(256) void k1_mfma(
    const unsigned short* __restrict__ Xb,   // [BTOK][256] bf16
    const unsigned short* __restrict__ Wp,   // [512][256] bf16 (re/im 16-interleaved)
    const float* __restrict__ bin, const float* __restrict__ dts,
    const float* __restrict__ decr, const float* __restrict__ deci,
    unsigned int* __restrict__ Xri)
{
  __shared__ __align__(16) unsigned short As[128 * 64];   // 16 KB
  __shared__ __align__(16) unsigned short Bs[128 * 64];   // 16 KB
  const int bx = blockIdx.x;
  const int wg = (bx & 7) * 128 + (bx >> 3);   // bijective: 1024 = 8 * 128
  const int mt = wg >> 2, nt = wg & 3;
  const int m0 = mt * 128, n0 = nt * 128;
  const int tid = threadIdx.x;
  const int lane = tid & 63, wid = tid >> 6;
  const int wr = wid >> 1, wc = wid & 1;
  const int l15 = lane & 15, hi = lane >> 4;
  const int lrow = tid >> 3;                  // 0..31
  const int sslot = (tid & 7) ^ (lrow & 7);   // inverse-swizzled source slot
  f32x4 acc[4][4];
  f32x4 z = {0.f, 0.f, 0.f, 0.f};
#pragma unroll
  for (int i = 0; i < 4; ++i)
#pragma unroll
    for (int j = 0; j < 4; ++j) acc[i][j] = z;

  for (int k0 = 0; k0 < 256; k0 += 64) {
    __syncthreads();
#pragma unroll
    for (int c = 0; c < 4; ++c) {
      gl_lds16(&Xb[(size_t)(m0 + c * 32 + lrow) * 256 + k0 + sslot * 8],
               &As[c * 2048 + tid * 8]);
      gl_lds16(&Wp[(size_t)(n0 + c * 32 + lrow) * 256 + k0 + sslot * 8],
               &Bs[c * 2048 + tid * 8]);
    }
    __syncthreads();
#pragma unroll
    for (int kk = 0; kk < 2; ++kk) {
      bf16x8 af[4], bfr[4];
      const int rslot = ((kk * 4 + hi) ^ (l15 & 7)) * 8;
#pragma unroll
      for (int m = 0; m < 4; ++m)
        af[m] = *reinterpret_cast<const bf16x8*>(&As[(wr * 64 + m * 16 + l15) * 64 + rslot]);
#pragma unroll
      for (int n = 0; n < 4; ++n)
        bfr[n] = *reinterpret_cast<const bf16x8*>(&Bs[(wc * 64 + n * 16 + l15) * 64 + rslot]);
#pragma unroll
      for (int m = 0; m < 4; ++m)
#pragma unroll
        for (int n = 0; n < 4; ++n)
          acc[m][n] = __builtin_amdgcn_mfma_f32_16x16x32_bf16(af[m], bfr[n], acc[m][n], 0, 0, 0);
    }
  }

  const int pbase = n0 + wc * 64;
#pragma unroll
  for (int pr = 0; pr < 2; ++pr) {
    const int d = (pbase >> 1) + pr * 16 + l15;
    const float nre = -softplusf(decr[d]);
    const float di = deci[d];
    const float br = bin[d], bi = bin[d + 256];
#pragma unroll
    for (int m = 0; m < 4; ++m) {
#pragma unroll
      for (int r = 0; r < 4; ++r) {
        const int row = m0 + wr * 64 + m * 16 + hi * 4 + r;
        float xr = acc[m][2 * pr][r] + br;
        float xi = acc[m][2 * pr + 1][r] + bi;
        float dt = dts[row];
        float are = nre * dt, aim = di * dt;
        float dr_, dm_, fr_, fm_;
        decay_forcing(are, aim, dr_, dm_, fr_, fm_);
        unsigned int pk = (unsigned int)f2bf(xr * fr_ - xi * fm_)
                        | ((unsigned int)f2bf(xr * fm_ + xi * fr_) << 16);
        Xri[(size_t)row * DD + d] = pk;
      }
    }
  }
}

// ---------------- K2 fused: chunk op + decoupled-lookback carry + apply ----------------
// 512 blocks = 8 batches x 64 chunks of 64 tokens. X held in registers (one Xri
// read total). Each block publishes its chunk operator with an AGENT-scope
// release flag; consumers acquire-spin (all 512 blocks co-resident at >=4
// blocks/CU, so no deadlock; waits ~0 since ops compute in parallel), fold
// predecessors in fixed order (bit-identical to the former k2a/k2c pair).
__global__ __launch_bounds__(256) void k2_scan(
    const unsigned int* __restrict__ Xri,    // [BTOK][256] packed bf16 re|im
    const float* __restrict__ dts, const float* __restrict__ decr,
    const float* __restrict__ deci,
    float4* __restrict__ ops, unsigned int* __restrict__ flags,
    unsigned short* __restrict__ F)
{
  const int bx = blockIdx.x;
  const int b = bx >> 6, c = bx & 63;
  const int d = threadIdx.x;
  __shared__ float sdt[64];
  if (threadIdx.x < 64) sdt[threadIdx.x] = dts[b * TT + c * 64 + threadIdx.x];
  const float nre = -softplusf(decr[d]);
  const float di = deci[d];
  __syncthreads();

  // ---- load X once into registers (static indexing, rule #20) ----
  unsigned int xs[64];
  const size_t gbase = (size_t)(b * TT + c * 64) * DD + d;
#pragma unroll
  for (int i = 0; i < 64; ++i) xs[i] = Xri[gbase + (size_t)i * DD];

  // ---- own chunk operator (A,B) ----
  float Ar = 1.f, Ai = 0.f, Br = 0.f, Bi = 0.f;
#pragma unroll
  for (int i = 0; i < 64; ++i) {
    float dt = sdt[i];
    float e = __expf(nre * dt);
    float s = __sinf(di * dt), cs = __cosf(di * dt);
    float ar = e * cs, ai = e * s;
    float xr = bf2f((unsigned short)(xs[i] & 0xffffu));
    float xi = bf2f((unsigned short)(xs[i] >> 16));
    float nAr = Ar * ar - Ai * ai, nAi = Ar * ai + Ai * ar;
    Ar = nAr; Ai = nAi;
    float nBr = Br * ar - Bi * ai + xr, nBi = Br * ai + Bi * ar + xi;
    Br = nBr; Bi = nBi;
  }
  ops[(size_t)bx * DD + d] = make_float4(Ar, Ai, Br, Bi);
  __syncthreads();   // all waves' ops stores drained (compiler emits vmcnt(0) before barrier)
  if (threadIdx.x == 0)
    __hip_atomic_store(&flags[bx], 1u, __ATOMIC_RELEASE, __HIP_MEMORY_SCOPE_AGENT);

  // ---- lookback: wait for predecessors' flags (threads 0..c-1, all in wave 0) ----
  if (threadIdx.x < c) {
    while (__hip_atomic_load(&flags[(b << 6) + threadIdx.x], __ATOMIC_ACQUIRE,
                             __HIP_MEMORY_SCOPE_AGENT) == 0u) {
      __builtin_amdgcn_s_sleep(2);
    }
  }
  __syncthreads();

  // ---- fold predecessor operators (fixed order 0..c-1; 8-wide prefetch) ----
  float hr = 0.f, hi2 = 0.f;
  const size_t obase = (size_t)(b * 64) * DD + d;
  for (int c0 = 0; c0 < c; c0 += 8) {
    float4 oo[8];
#pragma unroll
    for (int j = 0; j < 8; ++j)
      oo[j] = (c0 + j < c) ? ops[obase + (size_t)(c0 + j) * DD]
                           : make_float4(1.f, 0.f, 0.f, 0.f);
#pragma unroll
    for (int j = 0; j < 8; ++j) {
      float nr = oo[j].x * hr - oo[j].y * hi2 + oo[j].z;
      float ni = oo[j].x * hi2 + oo[j].y * hr + oo[j].w;
      hr = nr; hi2 = ni;
    }
  }

  // ---- apply chunk from register-held X; write flux packed [token][512] bf16 ----
  const int tok0 = b * TT + c * 64;
#pragma unroll
  for (int i = 0; i < 64; ++i) {
    float dt = sdt[i];
    float e = __expf(nre * dt);
    float s = __sinf(di * dt), cs = __cosf(di * dt);
    float ar = e * cs, ai = e * s;
    float xr = bf2f((unsigned short)(xs[i] & 0xffffu));
    float xi = bf2f((unsigned short)(xs[i] >> 16));
    float nr = ar * hr - ai * hi2 + xr;
    float ni = ar * hi2 + ai * hr + xi;
    hr = nr; hi2 = ni;
    size_t fb = (size_t)(tok0 + i) * 512 + d;
    F[fb] = f2bf(hr);
    F[fb + 256] = f2bf(hi2);
  }
}

// ---------------- K3+K4 fused launch, INTERLEAVED block mapping ----------------
// 2560 blocks = 512 groups of 5: positions 0-2 -> GEMM wg = 3q+r (1536 total),
// positions 3-4 -> prop pb = 2q+(r-3) (1024 total).
__global__ __launch_bounds__(256) void k3k4(
    const unsigned short* __restrict__ F,    // [BTOK][512] bf16
    const unsigned short* __restrict__ Wp,   // [768][512] bf16
    const float* __restrict__ bout, const float* __restrict__ bgate,
    const float* __restrict__ dts, const float* __restrict__ lre,
    const float* __restrict__ lim,
    float* __restrict__ out)
{
  __shared__ __align__(16) unsigned short As[128 * 64];
  __shared__ __align__(16) unsigned short Bs[128 * 64];

  const int q = blockIdx.x / 5, r5 = blockIdx.x % 5;

  if (r5 >= 3) {
    // ---- prop planes: pb in 0..1023, 32 tokens each ----
    const int pb = q * 2 + (r5 - 3);
    const int d = threadIdx.x;
    const float nl = -softplusf(lre[d]);
    const float li = lim[d];
    const int tok0 = pb * 32;
#pragma unroll 4
    for (int i = 0; i < 32; ++i) {
      const int tok = tok0 + i;
      float dt = dts[tok];
      float dr, dm, fr, fm;
      decay_forcing(nl * dt, li * dt, dr, dm, fr, fm);
      float* o = out + (size_t)tok * 1792 + 768;
      o[d] = dr; o[256 + d] = dm; o[512 + d] = fr; o[768 + d] = fm;
    }
    return;
  }

  const int gw = q * 3 + r5;                    // 0..1535
  const int wg = (gw & 7) * 192 + (gw >> 3);    // bijective XCD swizzle: 1536 = 8*192
  const int mt = wg / 6, nt = wg % 6;
  const int m0 = mt * 128, n0 = nt * 128;
  const int tid = threadIdx.x;
  const int lane = tid & 63, wid = tid >> 6;
  const int wr = wid >> 1, wc = wid & 1;
  const int l15 = lane & 15, hi = lane >> 4;
  const int lrow = tid >> 3;
  const int sslot = (tid & 7) ^ (lrow & 7);
  f32x4 acc[4][4];
  f32x4 z = {0.f, 0.f, 0.f, 0.f};
#pragma unroll
  for (int i = 0; i < 4; ++i)
#pragma unroll
    for (int j = 0; j < 4; ++j) acc[i][j] = z;

  for (int k0 = 0; k0 < 512; k0 += 64) {
    __syncthreads();
#pragma unroll
    for (int c = 0; c < 4; ++c) {
      gl_lds16(&F[(size_t)(m0 + c * 32 + lrow) * 512 + k0 + sslot * 8],
               &As[c * 2048 + tid * 8]);
      gl_lds16(&Wp[(size_t)(n0 + c * 32 + lrow) * 512 + k0 + sslot * 8],
               &Bs[c * 2048 + tid * 8]);
    }
    __syncthreads();
#pragma unroll
    for (int kk = 0; kk < 2; ++kk) {
      bf16x8 af[4], bfr[4];
      const int rslot = ((kk * 4 + hi) ^ (l15 & 7)) * 8;
#pragma unroll
      for (int m = 0; m < 4; ++m)
        af[m] = *reinterpret_cast<const bf16x8*>(&As[(wr * 64 + m * 16 + l15) * 64 + rslot]);
#pragma unroll
      for (int n = 0; n < 4; ++n)
        bfr[n] = *reinterpret_cast<const bf16x8*>(&Bs[(wc * 64 + n * 16 + l15) * 64 + rslot]);
#pragma unroll
      for (int m = 0; m < 4; ++m)
#pragma unroll
        for (int n = 0; n < 4; ++n)
          acc[m][n] = __builtin_amdgcn_mfma_f32_16x16x32_bf16(af[m], bfr[n], acc[m][n], 0, 0, 0);
    }
  }

  const int nb = n0 + wc * 64;   // wave-uniform: whole wave is src or gate
  if (nb < 512) {
#pragma unroll
    for (int j = 0; j < 4; ++j) {
      const int col = nb + j * 16 + l15;
      const float bb = bout[col];
#pragma unroll
      for (int m = 0; m < 4; ++m)
#pragma unroll
        for (int r = 0; r < 4; ++r) {
          const int row = m0 + wr * 64 + m * 16 + hi * 4 + r;
          out[(size_t)row * 1792 + col] = acc[m][j][r] + bb;
        }
    }
  } else {
#pragma unroll
    for (int j = 0; j < 4; ++j) {
      const int col = nb + j * 16 + l15;
      const float bb = bgate[col - 512];
#pragma unroll
      for (int m = 0; m < 4; ++m)
#pragma unroll
        for (int r = 0; r < 4; ++r) {
          const int row = m0 + wr * 64 + m * 16 + hi * 4 + r;
          float g = __builtin_amdgcn_rcpf(1.f + __expf(-(acc[m][j][r] + bb)));
          out[(size_t)row * 1792 + col] = g * 0.98f + 0.01f;
        }
    }
  }
}

// ---------------- launch ----------------
extern "C" void kernel_launch(void* const* d_in, const int* in_sizes, int n_in,
                              void* d_out, int out_size, void* d_ws, size_t ws_size,
                              hipStream_t stream)
{
  const float* x     = (const float*)d_in[0];
  const float* dts   = (const float*)d_in[1];
  const float* decr  = (const float*)d_in[2];
  const float* deci  = (const float*)d_in[3];
  const float* Win   = (const float*)d_in[4];
  const float* bin   = (const float*)d_in[5];
  const float* Wout  = (const float*)d_in[6];
  const float* bout  = (const float*)d_in[7];
  const float* Wgate = (const float*)d_in[8];
  const float* bgate = (const float*)d_in[9];
  const float* lre   = (const float*)d_in[10];
  const float* lim   = (const float*)d_in[11];
  float* out = (float*)d_out;
  char* ws = (char*)d_ws;

  // Workspace layout (~67 MB):
  //   F     [0, 32MB)      bf16 [BTOK][512] flux packed
  //   Xb    [16MB, 32MB)   bf16 [BTOK][256] — aliases F upper half; dead after k1
  //   Xri   [32MB, 64MB)   uint [BTOK][256] packed X_scan (re|im bf16)
  //   Wp1   [64MB, +256KB) bf16 [512][256]
  //   Wp3   [+, +768KB)    bf16 [768][512]
  //   ops   [65MB, +2MB)   float4 [512*256]
  //   flags [67MB, +2KB)   uint [512] — lookback ready flags (zeroed per launch)
  unsigned short* F   = (unsigned short*)(ws);
  unsigned short* Xb  = (unsigned short*)(ws + (size_t)16 * 1024 * 1024);
  unsigned int*  Xri  = (unsigned int*)(ws + (size_t)32 * 1024 * 1024);
  unsigned short* Wp1 = (unsigned short*)(ws + (size_t)64 * 1024 * 1024);
  unsigned short* Wp3 = (unsigned short*)(ws + (size_t)64 * 1024 * 1024 + 262144);
  float4* ops = (float4*)(ws + (size_t)65 * 1024 * 1024);
  unsigned int* flags = (unsigned int*)(ws + (size_t)67 * 1024 * 1024);

  hipMemsetAsync(flags, 0, 512 * sizeof(unsigned int), stream);
  prep<<<9472, 256, 0, stream>>>(x, Xb, Win, Wp1, Wout, Wgate, Wp3);
  k1_mfma<<<1024, 256, 0, stream>>>(Xb, Wp1, bin, dts, decr, deci, Xri);
  k2_scan<<<512, 256, 0, stream>>>(Xri, dts, decr, deci, ops, flags, F);
  k3k4<<<2560, 256, 0, stream>>>(F, Wp3, bout, bgate, dts, lre, lim, out);
}

// Round 13
// 124.634 us; speedup vs baseline: 1.2230x; 1.2230x over previous
//
#include <hip/hip_runtime.h>
#include <math.h>

// Problem constants
#define DD 256
#define TT 4096
#define NBATCH 8
#define BTOK 32768            // NBATCH*TT tokens
#define EPSF 1e-7f

typedef __attribute__((ext_vector_type(4))) float f32x4;
typedef __attribute__((ext_vector_type(8))) short bf16x8;

// ---------------- fast-math helpers (native v_exp/v_sin/v_cos/v_log/v_rcp) ----------------
__device__ __forceinline__ float softplusf(float x) {
  float e = __expf(-fabsf(x));
  return fmaxf(x, 0.f) + __logf(1.f + e);
}
__device__ __forceinline__ float bf2f(unsigned short u) {
  union { unsigned int i; float f; } v; v.i = ((unsigned int)u) << 16; return v.f;
}
__device__ __forceinline__ unsigned short f2bf(float f) {  // RTNE
  union { float f; unsigned int i; } v; v.f = f;
  unsigned int x = v.i;
  unsigned int lsb = (x >> 16) & 1u;
  x += 0x7fffu + lsb;
  return (unsigned short)(x >> 16);
}
// decay = exp(are + i*aim); forcing = (decay-1)/(exp_arg + eps*sign(re+eps))
__device__ __forceinline__ void decay_forcing(float are, float aim,
    float& dre, float& dim, float& fre, float& fim) {
  float e = __expf(are);
  float s = __sinf(aim), c = __cosf(aim);
  dre = e * c; dim = e * s;
  float sg = (are + EPSF >= 0.f) ? 1.f : -1.f;
  float denr = are + EPSF * sg;
  float deni = aim;
  float inv = __builtin_amdgcn_rcpf(denr * denr + deni * deni);
  float nr = dre - 1.f, ni = dim;
  fre = (nr * denr + ni * deni) * inv;
  fim = (ni * denr - nr * deni) * inv;
}
// async 16B global->LDS (linear dest: wave-uniform base + lane*16)
__device__ __forceinline__ void gl_lds16(const void* g, void* l) {
  __builtin_amdgcn_global_load_lds(
      (const __attribute__((address_space(1))) unsigned int*)g,
      (__attribute__((address_space(3))) unsigned int*)l, 16, 0, 0);
}

// ---------------- prep: xcvt (8192 blocks) | wpack1 (512) ----------------
__global__ __launch_bounds__(256) void prep(
    const float* __restrict__ x, unsigned short* __restrict__ Xb,
    const float* __restrict__ Win, unsigned short* __restrict__ Wp1)
{
  const int bid = blockIdx.x;
  if (bid < 8192) {
    size_t i = ((size_t)bid * 256 + threadIdx.x) * 4;
    float4 v = *reinterpret_cast<const float4*>(&x[i]);
    ushort4 u;
    u.x = f2bf(v.x); u.y = f2bf(v.y); u.z = f2bf(v.z); u.w = f2bf(v.w);
    *reinterpret_cast<ushort4*>(&Xb[i]) = u;
  } else {
    const int p = bid - 8192;          // 0..511
    const int k = threadIdx.x;         // 0..255
    const int g = p >> 5, r = p & 31;
    const int src = (r < 16) ? (g * 16 + r) : (256 + g * 16 + (r - 16));
    Wp1[(size_t)p * 256 + k] = f2bf(Win[(size_t)src * 512 + k]);
  }
}

// ---------------- K1: MFMA GEMM (M=32768, K=256, N=512 packed) + forcing epilogue ----------------
// Epilogue writes X_scan packed (re|im bf16 in one uint) -> Xri [BTOK][256].
__global__ __launch_bounds__(256) void k1_mfma(
    const unsigned short* __restrict__ Xb,   // [BTOK][256] bf16
    const unsigned short* __restrict__ Wp,   // [512][256] bf16 (re/im 16-interleaved)
    const float* __restrict__ bin, const float* __restrict__ dts,
    const float* __restrict__ decr, const float* __restrict__ deci,
    unsigned int* __restrict__ Xri)
{
  __shared__ __align__(16) unsigned short As[128 * 64];   // 16 KB
  __shared__ __align__(16) unsigned short Bs[128 * 64];   // 16 KB
  const int bx = blockIdx.x;
  const int wg = (bx & 7) * 128 + (bx >> 3);   // bijective: 1024 = 8 * 128
  const int mt = wg >> 2, nt = wg & 3;
  const int m0 = mt * 128, n0 = nt * 128;
  const int tid = threadIdx.x;
  const int lane = tid & 63, wid = tid >> 6;
  const int wr = wid >> 1, wc = wid & 1;
  const int l15 = lane & 15, hi = lane >> 4;
  const int lrow = tid >> 3;                  // 0..31
  const int sslot = (tid & 7) ^ (lrow & 7);   // inverse-swizzled source slot
  f32x4 acc[4][4];
  f32x4 z = {0.f, 0.f, 0.f, 0.f};
#pragma unroll
  for (int i = 0; i < 4; ++i)
#pragma unroll
    for (int j = 0; j < 4; ++j) acc[i][j] = z;

  for (int k0 = 0; k0 < 256; k0 += 64) {
    __syncthreads();
#pragma unroll
    for (int c = 0; c < 4; ++c) {
      gl_lds16(&Xb[(size_t)(m0 + c * 32 + lrow) * 256 + k0 + sslot * 8],
               &As[c * 2048 + tid * 8]);
      gl_lds16(&Wp[(size_t)(n0 + c * 32 + lrow) * 256 + k0 + sslot * 8],
               &Bs[c * 2048 + tid * 8]);
    }
    __syncthreads();
#pragma unroll
    for (int kk = 0; kk < 2; ++kk) {
      bf16x8 af[4], bfr[4];
      const int rslot = ((kk * 4 + hi) ^ (l15 & 7)) * 8;
#pragma unroll
      for (int m = 0; m < 4; ++m)
        af[m] = *reinterpret_cast<const bf16x8*>(&As[(wr * 64 + m * 16 + l15) * 64 + rslot]);
#pragma unroll
      for (int n = 0; n < 4; ++n)
        bfr[n] = *reinterpret_cast<const bf16x8*>(&Bs[(wc * 64 + n * 16 + l15) * 64 + rslot]);
#pragma unroll
      for (int m = 0; m < 4; ++m)
#pragma unroll
        for (int n = 0; n < 4; ++n)
          acc[m][n] = __builtin_amdgcn_mfma_f32_16x16x32_bf16(af[m], bfr[n], acc[m][n], 0, 0, 0);
    }
  }

  const int pbase = n0 + wc * 64;
#pragma unroll
  for (int pr = 0; pr < 2; ++pr) {
    const int d = (pbase >> 1) + pr * 16 + l15;
    const float nre = -softplusf(decr[d]);
    const float di = deci[d];
    const float br = bin[d], bi = bin[d + 256];
#pragma unroll
    for (int m = 0; m < 4; ++m) {
#pragma unroll
      for (int r = 0; r < 4; ++r) {
        const int row = m0 + wr * 64 + m * 16 + hi * 4 + r;
        float xr = acc[m][2 * pr][r] + br;
        float xi = acc[m][2 * pr + 1][r] + bi;
        float dt = dts[row];
        float are = nre * dt, aim = di * dt;
        float dr_, dm_, fr_, fm_;
        decay_forcing(are, aim, dr_, dm_, fr_, fm_);
        unsigned int pk = (unsigned int)f2bf(xr * fr_ - xi * fm_)
                        | ((unsigned int)f2bf(xr * fm_ + xi * fr_) << 16);
        Xri[(size_t)row * DD + d] = pk;
      }
    }
  }
}

// ---------------- K2a (+ wpack3 interleaved): per-chunk scan operators ----------------
// Blocks [0,512): chunk ops (critical path, dispatched first).
// Blocks [512,1280): pack Wout/Wgate -> Wp3 (first consumed by k3k4).
__global__ __launch_bounds__(256) void k2a_wp3(
    const unsigned int* __restrict__ Xri,    // [BTOK][256] packed bf16 re|im
    const float* __restrict__ dts, const float* __restrict__ decr,
    const float* __restrict__ deci,
    float4* __restrict__ ops,
    const float* __restrict__ Wout, const float* __restrict__ Wgate,
    unsigned short* __restrict__ Wp3)
{
  const int bx = blockIdx.x;
  if (bx >= 512) {
    const int p = bx - 512;            // 0..767
    const float* src = (p < 512) ? (Wout + (size_t)p * 512)
                                 : (Wgate + (size_t)(p - 512) * 512);
    Wp3[(size_t)p * 512 + threadIdx.x] = f2bf(src[threadIdx.x]);
    Wp3[(size_t)p * 512 + threadIdx.x + 256] = f2bf(src[threadIdx.x + 256]);
    return;
  }
  const int b = bx >> 6, c = bx & 63;
  const int d = threadIdx.x;
  __shared__ float sdt[64];
  if (threadIdx.x < 64) sdt[threadIdx.x] = dts[b * TT + c * 64 + threadIdx.x];
  const float nre = -softplusf(decr[d]);
  const float di = deci[d];
  __syncthreads();
  float Ar = 1.f, Ai = 0.f, Br = 0.f, Bi = 0.f;
  size_t base = (size_t)(b * TT + c * 64) * DD + d;
  for (int i = 0; i < 64; ++i) {
    float dt = sdt[i];
    float e = __expf(nre * dt);
    float s = __sinf(di * dt), cs = __cosf(di * dt);
    float ar = e * cs, ai = e * s;
    unsigned int pk = Xri[base]; base += DD;
    float xr = bf2f((unsigned short)(pk & 0xffffu));
    float xi = bf2f((unsigned short)(pk >> 16));
    float nAr = Ar * ar - Ai * ai, nAi = Ar * ai + Ai * ar;
    Ar = nAr; Ai = nAi;
    float nBr = Br * ar - Bi * ai + xr, nBi = Br * ai + Bi * ar + xi;
    Br = nBr; Bi = nBi;
  }
  ops[(size_t)bx * DD + d] = make_float4(Ar, Ai, Br, Bi);
}

// ---------------- K2c: self-scan carry (reads <=63 chunk ops) + apply; write F ----------------
__global__ __launch_bounds__(256) void k2c_apply(
    const unsigned int* __restrict__ Xri,
    const float* __restrict__ dts, const float* __restrict__ decr,
    const float* __restrict__ deci,
    const float4* __restrict__ ops,
    unsigned short* __restrict__ F)
{
  const int bx = blockIdx.x;
  const int b = bx >> 6, c = bx & 63;
  const int d = threadIdx.x;
  __shared__ float sdt[64];
  if (threadIdx.x < 64) sdt[threadIdx.x] = dts[b * TT + c * 64 + threadIdx.x];
  const float nre = -softplusf(decr[d]);
  const float di = deci[d];
  __syncthreads();

  // ---- self-scan carry over chunks 0..c-1 (L2-hot, 8-wide prefetch) ----
  float hr = 0.f, hi2 = 0.f;
  const size_t obase = (size_t)(b * 64) * DD + d;
  for (int c0 = 0; c0 < c; c0 += 8) {
    float4 oo[8];
#pragma unroll
    for (int j = 0; j < 8; ++j)
      oo[j] = (c0 + j < c) ? ops[obase + (size_t)(c0 + j) * DD]
                           : make_float4(1.f, 0.f, 0.f, 0.f);
#pragma unroll
    for (int j = 0; j < 8; ++j) {
      float nr = oo[j].x * hr - oo[j].y * hi2 + oo[j].z;
      float ni = oo[j].x * hi2 + oo[j].y * hr + oo[j].w;
      hr = nr; hi2 = ni;
    }
  }

  // ---- apply chunk ----
  const int tok0 = b * TT + c * 64;
  size_t base = (size_t)tok0 * DD + d;
  for (int i = 0; i < 64; ++i) {
    float dt = sdt[i];
    float e = __expf(nre * dt);
    float s = __sinf(di * dt), cs = __cosf(di * dt);
    float ar = e * cs, ai = e * s;
    unsigned int pk = Xri[base]; base += DD;
    float xr = bf2f((unsigned short)(pk & 0xffffu));
    float xi = bf2f((unsigned short)(pk >> 16));
    float nr = ar * hr - ai * hi2 + xr;
    float ni = ar * hi2 + ai * hr + xi;
    hr = nr; hi2 = ni;
    size_t fb = (size_t)(tok0 + i) * 512 + d;
    F[fb] = f2bf(hr);
    F[fb + 256] = f2bf(hi2);
  }
}

// ---------------- K3+K4 fused launch, INTERLEAVED block mapping ----------------
// 2560 blocks = 512 groups of 5: positions 0-2 -> GEMM wg = 3q+r (1536 total),
// positions 3-4 -> prop pb = 2q+(r-3) (1024 total). All `out` writes are
// non-temporal (out is never re-read) so F/Wp stay cache-resident.
__global__ __launch_bounds__(256) void k3k4(
    const unsigned short* __restrict__ F,    // [BTOK][512] bf16
    const unsigned short* __restrict__ Wp,   // [768][512] bf16
    const float* __restrict__ bout, const float* __restrict__ bgate,
    const float* __restrict__ dts, const float* __restrict__ lre,
    const float* __restrict__ lim,
    float* __restrict__ out)
{
  __shared__ __align__(16) unsigned short As[128 * 64];
  __shared__ __align__(16) unsigned short Bs[128 * 64];

  const int q = blockIdx.x / 5, r5 = blockIdx.x % 5;

  if (r5 >= 3) {
    // ---- prop planes: pb in 0..1023, 32 tokens each ----
    const int pb = q * 2 + (r5 - 3);
    const int d = threadIdx.x;
    const float nl = -softplusf(lre[d]);
    const float li = lim[d];
    const int tok0 = pb * 32;
#pragma unroll 4
    for (int i = 0; i < 32; ++i) {
      const int tok = tok0 + i;
      float dt = dts[tok];
      float dr, dm, fr, fm;
      decay_forcing(nl * dt, li * dt, dr, dm, fr, fm);
      float* o = out + (size_t)tok * 1792 + 768;
      __builtin_nontemporal_store(dr, &o[d]);
      __builtin_nontemporal_store(dm, &o[256 + d]);
      __builtin_nontemporal_store(fr, &o[512 + d]);
      __builtin_nontemporal_store(fm, &o[768 + d]);
    }
    return;
  }

  const int gw = q * 3 + r5;                    // 0..1535
  const int wg = (gw & 7) * 192 + (gw >> 3);    // bijective XCD swizzle: 1536 = 8*192
  const int mt = wg / 6, nt = wg % 6;
  const int m0 = mt * 128, n0 = nt * 128;
  const int tid = threadIdx.x;
  const int lane = tid & 63, wid = tid >> 6;
  const int wr = wid >> 1, wc = wid & 1;
  const int l15 = lane & 15, hi = lane >> 4;
  const int lrow = tid >> 3;
  const int sslot = (tid & 7) ^ (lrow & 7);
  f32x4 acc[4][4];
  f32x4 z = {0.f, 0.f, 0.f, 0.f};
#pragma unroll
  for (int i = 0; i < 4; ++i)
#pragma unroll
    for (int j = 0; j < 4; ++j) acc[i][j] = z;

  for (int k0 = 0; k0 < 512; k0 += 64) {
    __syncthreads();
#pragma unroll
    for (int c = 0; c < 4; ++c) {
      gl_lds16(&F[(size_t)(m0 + c * 32 + lrow) * 512 + k0 + sslot * 8],
               &As[c * 2048 + tid * 8]);
      gl_lds16(&Wp[(size_t)(n0 + c * 32 + lrow) * 512 + k0 + sslot * 8],
               &Bs[c * 2048 + tid * 8]);
    }
    __syncthreads();
    // T5: MFMA-cluster priority — pays here because GEMM and prop waves
    // co-reside on each CU (role diversity), unlike homogeneous GEMM (m190).
    __builtin_amdgcn_s_setprio(1);
#pragma unroll
    for (int kk = 0; kk < 2; ++kk) {
      bf16x8 af[4], bfr[4];
      const int rslot = ((kk * 4 + hi) ^ (l15 & 7)) * 8;
#pragma unroll
      for (int m = 0; m < 4; ++m)
        af[m] = *reinterpret_cast<const bf16x8*>(&As[(wr * 64 + m * 16 + l15) * 64 + rslot]);
#pragma unroll
      for (int n = 0; n < 4; ++n)
        bfr[n] = *reinterpret_cast<const bf16x8*>(&Bs[(wc * 64 + n * 16 + l15) * 64 + rslot]);
#pragma unroll
      for (int m = 0; m < 4; ++m)
#pragma unroll
        for (int n = 0; n < 4; ++n)
          acc[m][n] = __builtin_amdgcn_mfma_f32_16x16x32_bf16(af[m], bfr[n], acc[m][n], 0, 0, 0);
    }
    __builtin_amdgcn_s_setprio(0);
  }

  const int nb = n0 + wc * 64;   // wave-uniform: whole wave is src or gate
  if (nb < 512) {
#pragma unroll
    for (int j = 0; j < 4; ++j) {
      const int col = nb + j * 16 + l15;
      const float bb = bout[col];
#pragma unroll
      for (int m = 0; m < 4; ++m)
#pragma unroll
        for (int r = 0; r < 4; ++r) {
          const int row = m0 + wr * 64 + m * 16 + hi * 4 + r;
          __builtin_nontemporal_store(acc[m][j][r] + bb, &out[(size_t)row * 1792 + col]);
        }
    }
  } else {
#pragma unroll
    for (int j = 0; j < 4; ++j) {
      const int col = nb + j * 16 + l15;
      const float bb = bgate[col - 512];
#pragma unroll
      for (int m = 0; m < 4; ++m)
#pragma unroll
        for (int r = 0; r < 4; ++r) {
          const int row = m0 + wr * 64 + m * 16 + hi * 4 + r;
          float g = __builtin_amdgcn_rcpf(1.f + __expf(-(acc[m][j][r] + bb)));
          __builtin_nontemporal_store(g * 0.98f + 0.01f, &out[(size_t)row * 1792 + col]);
        }
    }
  }
}

// ---------------- launch ----------------
extern "C" void kernel_launch(void* const* d_in, const int* in_sizes, int n_in,
                              void* d_out, int out_size, void* d_ws, size_t ws_size,
                              hipStream_t stream)
{
  const float* x     = (const float*)d_in[0];
  const float* dts   = (const float*)d_in[1];
  const float* decr  = (const float*)d_in[2];
  const float* deci  = (const float*)d_in[3];
  const float* Win   = (const float*)d_in[4];
  const float* bin   = (const float*)d_in[5];
  const float* Wout  = (const float*)d_in[6];
  const float* bout  = (const float*)d_in[7];
  const float* Wgate = (const float*)d_in[8];
  const float* bgate = (const float*)d_in[9];
  const float* lre   = (const float*)d_in[10];
  const float* lim   = (const float*)d_in[11];
  float* out = (float*)d_out;
  char* ws = (char*)d_ws;

  // Workspace layout (~67 MB):
  //   F   [0, 32MB)      bf16 [BTOK][512] flux packed
  //   Xb  [16MB, 32MB)   bf16 [BTOK][256] — aliases F upper half; dead after k1
  //   Xri [32MB, 64MB)   uint [BTOK][256] packed X_scan (re|im bf16)
  //   Wp1 [64MB, +256KB) bf16 [512][256]
  //   Wp3 [+, +768KB)    bf16 [768][512]
  //   ops [65MB, +2MB)   float4 [512*256]
  unsigned short* F   = (unsigned short*)(ws);
  unsigned short* Xb  = (unsigned short*)(ws + (size_t)16 * 1024 * 1024);
  unsigned int*  Xri  = (unsigned int*)(ws + (size_t)32 * 1024 * 1024);
  unsigned short* Wp1 = (unsigned short*)(ws + (size_t)64 * 1024 * 1024);
  unsigned short* Wp3 = (unsigned short*)(ws + (size_t)64 * 1024 * 1024 + 262144);
  float4* ops = (float4*)(ws + (size_t)65 * 1024 * 1024);

  prep<<<8704, 256, 0, stream>>>(x, Xb, Win, Wp1);
  k1_mfma<<<1024, 256, 0, stream>>>(Xb, Wp1, bin, dts, decr, deci, Xri);
  k2a_wp3<<<1280, 256, 0, stream>>>(Xri, dts, decr, deci, ops, Wout, Wgate, Wp3);
  k2c_apply<<<512, 256, 0, stream>>>(Xri, dts, decr, deci, ops, F);
  k3k4<<<2560, 256, 0, stream>>>(F, Wp3, bout, bgate, dts, lre, lim, out);
}